// Round 8
// baseline (202.962 us; speedup 1.0000x reference)
//
#include <hip/hip_runtime.h>

#define BATCH 64
#define NN 512
#define DIMS 8
#define RDIM 514          // NN + 2
#define WB 51             // |i-j| <= 51  (0.1 * 511 = 51.1)
#define NDIAG (2 * NN - 1)            // 1023 real diagonals
#define DPAD 1024                     // padded diag count (diag 1023 = INF)
#define CHUNK 64
#define NCHUNK 16                     // 16 * 64 = 1024 padded diagonals

__device__ __forceinline__ int lo_of(int d) {
  int v = (d - (WB - 1)) >> 1;        // ceil((d-WB)/2)
  v = max(v, d - (NN - 1));
  return max(v, 0);
}
__device__ __forceinline__ int hi_of(int d) {
  return min(min(d, NN - 1), (d + WB) >> 1);
}

// DPP wave shifts (VALU). bound_ctrl=false + old => shifted-in lanes get `old`.
__device__ __forceinline__ float dpp_shr1(float x, float old) {  // lane i <- lane i-1
  return __int_as_float(__builtin_amdgcn_update_dpp(
      __float_as_int(old), __float_as_int(x), 0x138, 0xF, 0xF, false));
}
__device__ __forceinline__ float dpp_shl1(float x, float old) {  // lane i <- lane i+1
  return __int_as_float(__builtin_amdgcn_update_dpp(
      __float_as_int(old), __float_as_int(x), 0x130, 0xF, 0xF, false));
}

// ---------------------------------------------------------------------------
// Kernel 1: precompute banded D, LANE-MAJOR layout: Dws[b][l][n] (l = offset
// within diagonal, n = diagonal). Linear thread index == store index ->
// perfectly coalesced stores. Out-of-band / pad cells get +INF.
// ---------------------------------------------------------------------------
__global__ __launch_bounds__(256) void dpre_kernel(const float* __restrict__ X,
                                                   const float* __restrict__ Y,
                                                   float* __restrict__ Dws) {
  const int w = blockIdx.x * 256 + threadIdx.x;   // (b*64 + l)*1024 + n
  const int n = w & (DPAD - 1);
  const int l = (w >> 10) & 63;
  const int b = w >> 16;
  const int lon = lo_of(n);
  const int i = lon + l;
  const bool valid = (i <= hi_of(n)) && (n < NDIAG);
  const int ic = min(i, NN - 1);
  const int jc = min(max(n - ic, 0), NN - 1);
  const float4* xp = (const float4*)(X + ((size_t)b * NN + ic) * DIMS);
  const float4* yp = (const float4*)(Y + ((size_t)b * NN + jc) * DIMS);
  float4 xa = xp[0], xb = xp[1];
  float4 ya = yp[0], yb = yp[1];
  float x2 = xa.x * xa.x + xa.y * xa.y + xa.z * xa.z + xa.w * xa.w +
             xb.x * xb.x + xb.y * xb.y + xb.z * xb.z + xb.w * xb.w;
  float y2 = ya.x * ya.x + ya.y * ya.y + ya.z * ya.z + ya.w * ya.w +
             yb.x * yb.x + yb.y * yb.y + yb.z * yb.z + yb.w * yb.w;
  float dot = xa.x * ya.x + xa.y * ya.y + xa.z * ya.z + xa.w * ya.w +
              xb.x * yb.x + xb.y * yb.y + xb.z * yb.z + xb.w * yb.w;
  float D = (x2 + y2) - 2.0f * dot;   // mirrors reference expansion
  Dws[w] = valid ? D : __builtin_inff();
}

// ---------------------------------------------------------------------------
// Kernel 2: DTW sweep.
//  wave0:    register recurrence; D prefetched global->VGPR (16 dwordx4 per
//            chunk, double-buffered qA/qB, counted vmcnt). ONLY ds_write in
//            the loop. Chain: dpp -> cndmask -> min3 -> add.
//  waves1-3: write row-major band segments of chunk c-1 directly to Rfull
//            (transpose done through the padded Rring LDS tile).
// ---------------------------------------------------------------------------
__global__ __launch_bounds__(256) void dtw_ws_kernel(const float* __restrict__ Dws,
                                                     float* __restrict__ out) {
  __shared__ float Rring[2][CHUNK][65];   // padded: flusher reads stride-65
  const int b = blockIdx.x;
  const int t = threadIdx.x;
  const int wave = t >> 6, lane = t & 63;
  const float INF = __builtin_inff();

  const float* __restrict__ Db = Dws + (size_t)b * 64 * DPAD;
  float* __restrict__ Rfull = out + BATCH + (size_t)b * RDIM * RDIM;

  if (t == 64) Rfull[0] = 0.0f;   // R[b][0][0] = 0

  // wave0 persistent recurrence state.
  // shm_shr seeded so that at n=0 (d2==0 path) rmin = 0 at lane 0, INF else.
  float r_d = INF, r_dm1 = INF, shm_shl = INF;
  float shm_shr = (lane == 0) ? 0.0f : INF;
  int lop = 0, lopp = 0;

  float4 qA[16], qB[16];

  auto prefetchD = [&](float4 (&q)[16], int base) {
    const float4* s4 = (const float4*)(Db + (size_t)lane * DPAD + base);
#pragma unroll
    for (int k = 0; k < 16; ++k) q[k] = s4[k];
  };

  auto computeChunk = [&](const float4 (&q)[16], int c) {
    const int base = c * CHUNK;
    float* wr = &Rring[c & 1][0][lane];
#pragma unroll
    for (int m = 0; m < CHUNK; ++m) {
      const int n = base + m;
      const int lon = lo_of(n);
      const int d1 = lon - lop;          // {0,1}
      const int d2 = lon - lopp;         // {0,1,2}
      float s_shl = dpp_shl1(r_d, INF);
      float s_shr = dpp_shr1(r_d, INF);
      float tt = d1 ? s_shl : s_shr;     // covers both va/vb cases vs r_d
      float vc = (d2 == 0) ? shm_shr : ((d2 == 1) ? r_dm1 : shm_shl);
      float qm = (m & 3) == 0 ? q[m >> 2].x
               : (m & 3) == 1 ? q[m >> 2].y
               : (m & 3) == 2 ? q[m >> 2].z : q[m >> 2].w;
      float r = qm + fminf(fminf(r_d, tt), vc);   // INF in q encodes band
      wr[m * 65] = r;                             // ds_write, fire-and-forget
      r_dm1 = r_d; shm_shl = s_shl; shm_shr = s_shr; r_d = r;
      lopp = lop; lop = lon;
    }
  };

  if (wave == 0) prefetchD(qA, 0);

  for (int c = 0; c <= NCHUNK; ++c) {
    if (wave == 0) {
      if (c < NCHUNK) {
        const int nb = min((c + 1) * CHUNK, (NCHUNK - 1) * CHUNK);
        if (c & 1) { prefetchD(qA, nb); computeChunk(qB, c); }
        else       { prefetchD(qB, nb); computeChunk(qA, c); }
      }
    } else if (c >= 1) {
      // flush chunk c-1: row-major segments straight to Rfull
      const int cc = c - 1;
      const int buf = cc & 1;
      const int dlo = cc * CHUNK;
      const int dhi1 = min(dlo + CHUNK - 1, NDIAG - 1);
      const int rlo = lo_of(dlo), rhi = hi_of(dhi1);
      for (int i = rlo + (wave - 1); i <= rhi; i += 3) {
        const int j0 = max(max(i - WB, dlo - i), 0);
        const int j1 = min(min(i + WB, dhi1 - i), NN - 1);
        const int j = j0 + lane;
        if (j <= j1) {
          const int n = i + j;
          const int dd = n - dlo;
          const int l2 = i - lo_of(n);
          Rfull[(size_t)(i + 1) * RDIM + (j + 1)] = Rring[buf][dd][l2];
        }
      }
    }
    __syncthreads();
  }

  // after chunk 15: r_d = padded diag 1023 (INF), r_dm1 = diag 1022.
  if (t == 0) out[b] = r_dm1;   // lane0 of diag 1022 = R[511][511]
}

// ---------------------------------------------------------------------------
// Fallback (ws too small): proven R3-style kernel (no workspace needed).
// ---------------------------------------------------------------------------
__global__ __launch_bounds__(256) void dtw_fb_kernel(const float* __restrict__ X,
                                                     const float* __restrict__ Y,
                                                     float* __restrict__ out) {
  __shared__ float xsT[DIMS][NN];
  __shared__ float ysT[DIMS][NN];
  __shared__ float x2s[NN];
  __shared__ float y2s[NN];
  __shared__ float ring[2][CHUNK][64];

  const int b = blockIdx.x;
  const int t = threadIdx.x;
  const float INF = __builtin_inff();

  {
    const float4* Xg = (const float4*)(X + (size_t)b * NN * DIMS);
    const float4* Yg = (const float4*)(Y + (size_t)b * NN * DIMS);
    for (int r = t; r < NN; r += 256) {
      float4 a0 = Xg[2 * r], a1 = Xg[2 * r + 1];
      xsT[0][r] = a0.x; xsT[1][r] = a0.y; xsT[2][r] = a0.z; xsT[3][r] = a0.w;
      xsT[4][r] = a1.x; xsT[5][r] = a1.y; xsT[6][r] = a1.z; xsT[7][r] = a1.w;
      x2s[r] = a0.x * a0.x + a0.y * a0.y + a0.z * a0.z + a0.w * a0.w +
               a1.x * a1.x + a1.y * a1.y + a1.z * a1.z + a1.w * a1.w;
      float4 c0 = Yg[2 * r], c1 = Yg[2 * r + 1];
      ysT[0][r] = c0.x; ysT[1][r] = c0.y; ysT[2][r] = c0.z; ysT[3][r] = c0.w;
      ysT[4][r] = c1.x; ysT[5][r] = c1.y; ysT[6][r] = c1.z; ysT[7][r] = c1.w;
      y2s[r] = c0.x * c0.x + c0.y * c0.y + c0.z * c0.z + c0.w * c0.w +
               c1.x * c1.x + c1.y * c1.y + c1.z * c1.z + c1.w * c1.w;
    }
  }
  __syncthreads();

  float* __restrict__ Rfull = out + BATCH + (size_t)b * RDIM * RDIM;
  if (t == 64) Rfull[0] = 0.0f;

  const int lane = t & 63;
  float r_d = INF, r_dm1 = INF;
  int lop = 0, lopp = 0;
  float Dcur = 0.0f;
  if (t < 64) {
    int i0 = min(lane, NN - 1);
    int j0 = max(0, min(0 - i0, NN - 1));
    float dot = xsT[0][i0] * ysT[0][j0] + xsT[1][i0] * ysT[1][j0] +
                xsT[2][i0] * ysT[2][j0] + xsT[3][i0] * ysT[3][j0] +
                xsT[4][i0] * ysT[4][j0] + xsT[5][i0] * ysT[5][j0] +
                xsT[6][i0] * ysT[6][j0] + xsT[7][i0] * ysT[7][j0];
    Dcur = (x2s[i0] + y2s[j0]) - 2.0f * dot;
  }

  for (int c = 0; c <= NCHUNK; ++c) {
    if (t < 64 && c < NCHUNK) {
      const int dlo = c * CHUNK;
      const int dhi = min(dlo + CHUNK, NDIAG);
      for (int n = dlo; n < dhi; ++n) {
        const int lon = lo_of(n), hin = hi_of(n);
        const int d1 = lon - lop;
        const int d2 = lon - lopp;
        const int sa = lane + d1;
        const int sb = sa - 1;
        const int sc = lane + d2 - 1;
        float va = __shfl(r_d, sa);   va = (sa < 64) ? va : INF;
        float vb = __shfl(r_d, sb);   vb = (sb >= 0) ? vb : INF;
        float vc = __shfl(r_dm1, sc); vc = (sc >= 0 && sc < 64) ? vc : INF;
        float rmin = fminf(fminf(vc, vb), va);
        if (n == 0) rmin = (lane == 0) ? 0.0f : INF;
        float r = Dcur + rmin;
        if (lane > hin - lon) r = INF;
        ring[c & 1][n - dlo][lane] = r;
        const int lon1 = lo_of(n + 1);
        int ii = min(lon1 + lane, NN - 1);
        int jj = n + 1 - ii; jj = max(0, min(jj, NN - 1));
        float dot = xsT[0][ii] * ysT[0][jj] + xsT[1][ii] * ysT[1][jj] +
                    xsT[2][ii] * ysT[2][jj] + xsT[3][ii] * ysT[3][jj] +
                    xsT[4][ii] * ysT[4][jj] + xsT[5][ii] * ysT[5][jj] +
                    xsT[6][ii] * ysT[6][jj] + xsT[7][ii] * ysT[7][jj];
        Dcur = (x2s[ii] + y2s[jj]) - 2.0f * dot;
        r_dm1 = r_d; r_d = r;
        lopp = lop; lop = lon;
      }
    } else if (t >= 64 && c >= 1) {
      const int dlo = (c - 1) * CHUNK;
      const int dhi = min(dlo + CHUNK, NDIAG);
      const int nslots = (dhi - dlo) * 64;
      const int buf = (c - 1) & 1;
      for (int s = t - 64; s < nslots; s += 192) {
        const int dd = s >> 6, l2 = s & 63;
        const int n = dlo + dd;
        const int lon = lo_of(n);
        const int i = lon + l2;
        if (i <= hi_of(n)) {
          Rfull[(size_t)(i + 1) * RDIM + (n - i + 1)] = ring[buf][dd][l2];
        }
      }
    }
    __syncthreads();
  }

  if (t == 0) out[b] = r_d;
}

extern "C" void kernel_launch(void* const* d_in, const int* in_sizes, int n_in,
                              void* d_out, int out_size, void* d_ws, size_t ws_size,
                              hipStream_t stream) {
  const float* X = (const float*)d_in[0];
  const float* Y = (const float*)d_in[1];
  float* out = (float*)d_out;

  const size_t need = (size_t)BATCH * 64 * DPAD * sizeof(float);  // 16.78 MB
  if (ws_size >= need) {
    float* Dws = (float*)d_ws;
    dpre_kernel<<<(BATCH * 64 * DPAD) / 256, 256, 0, stream>>>(X, Y, Dws);
    dtw_ws_kernel<<<BATCH, 256, 0, stream>>>(Dws, out);
  } else {
    dtw_fb_kernel<<<BATCH, 256, 0, stream>>>(X, Y, out);
  }
}

// Round 9
// 110.227 us; speedup vs baseline: 1.8413x; 1.8413x over previous
//
#include <hip/hip_runtime.h>

#define BATCH 64
#define NN 512
#define DIMS 8
#define RDIM 514          // NN + 2
#define WB 51             // |i-j| <= 51  (0.1 * 511 = 51.1)
#define NDIAG (2 * NN - 1)            // 1023 real diagonals
#define DPAD 1024                     // padded diag count (diag 1023 = INF)
#define CHUNK 64
#define NCHUNK 16                     // 16 * 64 = 1024 padded diagonals

__device__ __forceinline__ int lo_of(int d) {
  int v = (d - (WB - 1)) >> 1;        // ceil((d-WB)/2)
  v = max(v, d - (NN - 1));
  return max(v, 0);
}
__device__ __forceinline__ int hi_of(int d) {
  return min(min(d, NN - 1), (d + WB) >> 1);
}

// DPP wave shifts (VALU). bound_ctrl=false + old => shifted-in lanes get `old`.
__device__ __forceinline__ float dpp_shr1(float x, float old) {  // lane i <- lane i-1
  return __int_as_float(__builtin_amdgcn_update_dpp(
      __float_as_int(old), __float_as_int(x), 0x138, 0xF, 0xF, false));
}
__device__ __forceinline__ float dpp_shl1(float x, float old) {  // lane i <- lane i+1
  return __int_as_float(__builtin_amdgcn_update_dpp(
      __float_as_int(old), __float_as_int(x), 0x130, 0xF, 0xF, false));
}

// ---------------------------------------------------------------------------
// Kernel 1: precompute banded D into Dws[b][n][lane], n in [0,1024), diag-major
// (proven R5/R7). Out-of-band lanes / padded diag get +INF.
// ---------------------------------------------------------------------------
__global__ __launch_bounds__(256) void dpre_kernel(const float* __restrict__ X,
                                                   const float* __restrict__ Y,
                                                   float* __restrict__ Dws) {
  const int w = blockIdx.x * 4 + (threadIdx.x >> 6);   // w in [0, BATCH*1024)
  const int lane = threadIdx.x & 63;
  const int b = w >> 10;
  const int n = w & 1023;
  const int lon = lo_of(n), hin = hi_of(n);
  const int i = lon + lane;
  const bool valid = (i <= hin) && (n < NDIAG);
  const int ic = min(i, NN - 1);
  const int jc = min(max(n - ic, 0), NN - 1);
  const float4* xp = (const float4*)(X + ((size_t)b * NN + ic) * DIMS);
  const float4* yp = (const float4*)(Y + ((size_t)b * NN + jc) * DIMS);
  float4 xa = xp[0], xb = xp[1];
  float4 ya = yp[0], yb = yp[1];
  float x2 = xa.x * xa.x + xa.y * xa.y + xa.z * xa.z + xa.w * xa.w +
             xb.x * xb.x + xb.y * xb.y + xb.z * xb.z + xb.w * xb.w;
  float y2 = ya.x * ya.x + ya.y * ya.y + ya.z * ya.z + ya.w * ya.w +
             yb.x * yb.x + yb.y * yb.y + yb.z * yb.z + yb.w * yb.w;
  float dot = xa.x * ya.x + xa.y * ya.y + xa.z * ya.z + xa.w * ya.w +
              xb.x * yb.x + xb.y * yb.y + xb.z * yb.z + xb.w * yb.w;
  float D = (x2 + y2) - 2.0f * dot;   // mirrors reference expansion
  Dws[((size_t)b * DPAD + n) * 64 + lane] = valid ? D : __builtin_inff();
}

// ---------------------------------------------------------------------------
// Kernel 2: bare-metal DTW sweep. ONE 64-thread wave per batch. No LDS, no
// barriers, no helper waves. q[m] slot reloaded (coalesced, next chunk) right
// after use -> ~2000 cyc latency cover. Stores fire-and-forget to Rdiag.
// ---------------------------------------------------------------------------
__global__ __launch_bounds__(64) void dtw_reg_kernel(const float* __restrict__ Dws,
                                                     float* __restrict__ Rdiag,
                                                     float* __restrict__ out) {
  const int b = blockIdx.x;
  const int lane = threadIdx.x;
  const float INF = __builtin_inff();

  const float* __restrict__ Db = Dws + (size_t)b * DPAD * 64;
  float* __restrict__ Rd = Rdiag + (size_t)b * DPAD * 64;

  float q[CHUNK];
#pragma unroll
  for (int m = 0; m < CHUNK; ++m) q[m] = Db[m * 64 + lane];   // chunk 0, coalesced

  // persistent recurrence state (proven R5/R7 lineage).
  // shm_shr seeded so that at n=0 (d2==0 path) rmin = 0 at lane 0, INF else.
  float r_d = INF, r_dm1 = INF, shm_shl = INF;
  float shm_shr = (lane == 0) ? 0.0f : INF;
  int lop = 0, lopp = 0;

  for (int c = 0; c < NCHUNK; ++c) {
    const int base = c * CHUNK;
#pragma unroll
    for (int m = 0; m < CHUNK; ++m) {
      const int n = base + m;
      const int lon = lo_of(n);
      const int d1 = lon - lop;          // {0,1}
      const int d2 = lon - lopp;         // {0,1,2}
      float s_shl = dpp_shl1(r_d, INF);
      float s_shr = dpp_shr1(r_d, INF);
      float tt = d1 ? s_shl : s_shr;     // min(va,vb) == min(r_d, tt)
      float vc = (d2 == 0) ? shm_shr : ((d2 == 1) ? r_dm1 : shm_shl);
      float r = q[m] + fminf(fminf(r_d, tt), vc);   // INF in q encodes band
      Rd[(size_t)n * 64 + lane] = r;                // coalesced, fire-and-forget
      const int nn = min(n + CHUNK, DPAD - 1);      // prefetch next chunk's slot
      q[m] = Db[(size_t)nn * 64 + lane];
      r_dm1 = r_d; shm_shl = s_shl; shm_shr = s_shr; r_d = r;
      lopp = lop; lop = lon;
    }
  }

  // after chunk 15: r_d = padded diag 1023 (INF), r_dm1 = diag 1022.
  if (lane == 0) out[b] = r_dm1;   // lane0 of diag 1022 = R[511][511]
}

// ---------------------------------------------------------------------------
// Kernel 3: transpose Rdiag (diag-major) -> Rfull rows (coalesced both ways).
// Block = (batch, chunk). LDS tile padded [64][65]. (proven R6/R7)
// ---------------------------------------------------------------------------
__global__ __launch_bounds__(256) void transpose_kernel(const float* __restrict__ Rdiag,
                                                        float* __restrict__ out) {
  __shared__ float T[CHUNK][65];
  const int b = blockIdx.x >> 4;
  const int cc = blockIdx.x & 15;
  const int t = threadIdx.x;
  const int w = t >> 6, lane = t & 63;

  float* __restrict__ Rfull = out + BATCH + (size_t)b * RDIM * RDIM;
  if (cc == 0 && t == 0) Rfull[0] = 0.0f;   // R[b][0][0] = 0

  const float4* src4 = (const float4*)(Rdiag + ((size_t)b * DPAD + cc * CHUNK) * 64);
#pragma unroll
  for (int k = 0; k < 4; ++k) {
    const int idx4 = t + k * 256;            // 1024 float4 = 4096 floats
    float4 f = src4[idx4];
    const int linear = idx4 * 4;
    const int dd = linear >> 6, l = linear & 63;
    T[dd][l] = f.x; T[dd][l + 1] = f.y; T[dd][l + 2] = f.z; T[dd][l + 3] = f.w;
  }
  __syncthreads();

  const int dlo = cc * CHUNK;
  const int dhi1 = min(dlo + CHUNK - 1, NDIAG - 1);   // last real diag in chunk
  const int rlo = lo_of(dlo);
  const int rhi = hi_of(dhi1);

  for (int i = rlo + w; i <= rhi; i += 4) {
    const int j0 = max(max(i - WB, dlo - i), 0);
    const int j1 = min(min(i + WB, dhi1 - i), NN - 1);
    const int j = j0 + lane;
    if (j <= j1) {
      const int n = i + j;
      const int dd = n - dlo;
      const int l2 = i - lo_of(n);
      Rfull[(size_t)(i + 1) * RDIM + (j + 1)] = T[dd][l2];
    }
  }
}

// ---------------------------------------------------------------------------
// Fallback (ws too small): proven R3-style kernel (no workspace needed).
// ---------------------------------------------------------------------------
__global__ __launch_bounds__(256) void dtw_fb_kernel(const float* __restrict__ X,
                                                     const float* __restrict__ Y,
                                                     float* __restrict__ out) {
  __shared__ float xsT[DIMS][NN];
  __shared__ float ysT[DIMS][NN];
  __shared__ float x2s[NN];
  __shared__ float y2s[NN];
  __shared__ float ring[2][CHUNK][64];

  const int b = blockIdx.x;
  const int t = threadIdx.x;
  const float INF = __builtin_inff();

  {
    const float4* Xg = (const float4*)(X + (size_t)b * NN * DIMS);
    const float4* Yg = (const float4*)(Y + (size_t)b * NN * DIMS);
    for (int r = t; r < NN; r += 256) {
      float4 a0 = Xg[2 * r], a1 = Xg[2 * r + 1];
      xsT[0][r] = a0.x; xsT[1][r] = a0.y; xsT[2][r] = a0.z; xsT[3][r] = a0.w;
      xsT[4][r] = a1.x; xsT[5][r] = a1.y; xsT[6][r] = a1.z; xsT[7][r] = a1.w;
      x2s[r] = a0.x * a0.x + a0.y * a0.y + a0.z * a0.z + a0.w * a0.w +
               a1.x * a1.x + a1.y * a1.y + a1.z * a1.z + a1.w * a1.w;
      float4 c0 = Yg[2 * r], c1 = Yg[2 * r + 1];
      ysT[0][r] = c0.x; ysT[1][r] = c0.y; ysT[2][r] = c0.z; ysT[3][r] = c0.w;
      ysT[4][r] = c1.x; ysT[5][r] = c1.y; ysT[6][r] = c1.z; ysT[7][r] = c1.w;
      y2s[r] = c0.x * c0.x + c0.y * c0.y + c0.z * c0.z + c0.w * c0.w +
               c1.x * c1.x + c1.y * c1.y + c1.z * c1.z + c1.w * c1.w;
    }
  }
  __syncthreads();

  float* __restrict__ Rfull = out + BATCH + (size_t)b * RDIM * RDIM;
  if (t == 64) Rfull[0] = 0.0f;

  const int lane = t & 63;
  float r_d = INF, r_dm1 = INF;
  int lop = 0, lopp = 0;
  float Dcur = 0.0f;
  if (t < 64) {
    int i0 = min(lane, NN - 1);
    int j0 = max(0, min(0 - i0, NN - 1));
    float dot = xsT[0][i0] * ysT[0][j0] + xsT[1][i0] * ysT[1][j0] +
                xsT[2][i0] * ysT[2][j0] + xsT[3][i0] * ysT[3][j0] +
                xsT[4][i0] * ysT[4][j0] + xsT[5][i0] * ysT[5][j0] +
                xsT[6][i0] * ysT[6][j0] + xsT[7][i0] * ysT[7][j0];
    Dcur = (x2s[i0] + y2s[j0]) - 2.0f * dot;
  }

  for (int c = 0; c <= NCHUNK; ++c) {
    if (t < 64 && c < NCHUNK) {
      const int dlo = c * CHUNK;
      const int dhi = min(dlo + CHUNK, NDIAG);
      for (int n = dlo; n < dhi; ++n) {
        const int lon = lo_of(n), hin = hi_of(n);
        const int d1 = lon - lop;
        const int d2 = lon - lopp;
        const int sa = lane + d1;
        const int sb = sa - 1;
        const int sc = lane + d2 - 1;
        float va = __shfl(r_d, sa);   va = (sa < 64) ? va : INF;
        float vb = __shfl(r_d, sb);   vb = (sb >= 0) ? vb : INF;
        float vc = __shfl(r_dm1, sc); vc = (sc >= 0 && sc < 64) ? vc : INF;
        float rmin = fminf(fminf(vc, vb), va);
        if (n == 0) rmin = (lane == 0) ? 0.0f : INF;
        float r = Dcur + rmin;
        if (lane > hin - lon) r = INF;
        ring[c & 1][n - dlo][lane] = r;
        const int lon1 = lo_of(n + 1);
        int ii = min(lon1 + lane, NN - 1);
        int jj = n + 1 - ii; jj = max(0, min(jj, NN - 1));
        float dot = xsT[0][ii] * ysT[0][jj] + xsT[1][ii] * ysT[1][jj] +
                    xsT[2][ii] * ysT[2][jj] + xsT[3][ii] * ysT[3][jj] +
                    xsT[4][ii] * ysT[4][jj] + xsT[5][ii] * ysT[5][jj] +
                    xsT[6][ii] * ysT[6][jj] + xsT[7][ii] * ysT[7][jj];
        Dcur = (x2s[ii] + y2s[jj]) - 2.0f * dot;
        r_dm1 = r_d; r_d = r;
        lopp = lop; lop = lon;
      }
    } else if (t >= 64 && c >= 1) {
      const int dlo = (c - 1) * CHUNK;
      const int dhi = min(dlo + CHUNK, NDIAG);
      const int nslots = (dhi - dlo) * 64;
      const int buf = (c - 1) & 1;
      for (int s = t - 64; s < nslots; s += 192) {
        const int dd = s >> 6, l2 = s & 63;
        const int n = dlo + dd;
        const int lon = lo_of(n);
        const int i = lon + l2;
        if (i <= hi_of(n)) {
          Rfull[(size_t)(i + 1) * RDIM + (n - i + 1)] = ring[buf][dd][l2];
        }
      }
    }
    __syncthreads();
  }

  if (t == 0) out[b] = r_d;
}

extern "C" void kernel_launch(void* const* d_in, const int* in_sizes, int n_in,
                              void* d_out, int out_size, void* d_ws, size_t ws_size,
                              hipStream_t stream) {
  const float* X = (const float*)d_in[0];
  const float* Y = (const float*)d_in[1];
  float* out = (float*)d_out;

  const size_t needD = (size_t)BATCH * DPAD * 64 * sizeof(float);  // 16.78 MB
  const size_t need = 2 * needD;                                   // Dws + Rdiag
  if (ws_size >= need) {
    float* Dws = (float*)d_ws;
    float* Rdiag = (float*)d_ws + (size_t)BATCH * DPAD * 64;
    dpre_kernel<<<(BATCH * DPAD) / 4, 256, 0, stream>>>(X, Y, Dws);
    dtw_reg_kernel<<<BATCH, 64, 0, stream>>>(Dws, Rdiag, out);
    transpose_kernel<<<BATCH * NCHUNK, 256, 0, stream>>>(Rdiag, out);
  } else {
    dtw_fb_kernel<<<BATCH, 256, 0, stream>>>(X, Y, out);
  }
}

// Round 10
// 52.519 us; speedup vs baseline: 3.8645x; 2.0988x over previous
//
#include <hip/hip_runtime.h>

#define BATCH 64
#define NN 512
#define DIMS 8
#define RDIM 514          // NN + 2
#define WB 51             // |i-j| <= 51  (0.1 * 511 = 51.1)
#define NDIAG (2 * NN - 1)            // 1023 real diagonals
#define DPAD 1024                     // padded diag count (diag 1023 = INF)
#define CHUNK 64
#define NCHUNK 16                     // 16 * 64 = 1024 padded diagonals

__device__ __forceinline__ constexpr int lo_of(int d) {
  int v = (d - (WB - 1)) >> 1;        // floor((d-50)/2)
  int w = d - (NN - 1);
  v = v > w ? v : w;
  return v > 0 ? v : 0;
}
__device__ __forceinline__ int hi_of(int d) {
  return min(min(d, NN - 1), (d + WB) >> 1);
}

// DPP wave shifts (VALU). bound_ctrl=false + old => shifted-in lanes get `old`.
// Empirically validated R4-R9 (kernels pass vs reference).
__device__ __forceinline__ float dpp_shr1(float x, float old) {  // lane i <- lane i-1
  return __int_as_float(__builtin_amdgcn_update_dpp(
      __float_as_int(old), __float_as_int(x), 0x138, 0xF, 0xF, false));
}
__device__ __forceinline__ float dpp_shl1(float x, float old) {  // lane i <- lane i+1
  return __int_as_float(__builtin_amdgcn_update_dpp(
      __float_as_int(old), __float_as_int(x), 0x130, 0xF, 0xF, false));
}

// ---------------------------------------------------------------------------
// Kernel 1: precompute banded D into Dws[b][n][lane], diag-major (proven R5-R9).
// Out-of-band lanes / padded diag get +INF.
// ---------------------------------------------------------------------------
__global__ __launch_bounds__(256) void dpre_kernel(const float* __restrict__ X,
                                                   const float* __restrict__ Y,
                                                   float* __restrict__ Dws) {
  const int w = blockIdx.x * 4 + (threadIdx.x >> 6);   // w in [0, BATCH*1024)
  const int lane = threadIdx.x & 63;
  const int b = w >> 10;
  const int n = w & 1023;
  const int lon = lo_of(n), hin = hi_of(n);
  const int i = lon + lane;
  const bool valid = (i <= hin) && (n < NDIAG);
  const int ic = min(i, NN - 1);
  const int jc = min(max(n - ic, 0), NN - 1);
  const float4* xp = (const float4*)(X + ((size_t)b * NN + ic) * DIMS);
  const float4* yp = (const float4*)(Y + ((size_t)b * NN + jc) * DIMS);
  float4 xa = xp[0], xb = xp[1];
  float4 ya = yp[0], yb = yp[1];
  float x2 = xa.x * xa.x + xa.y * xa.y + xa.z * xa.z + xa.w * xa.w +
             xb.x * xb.x + xb.y * xb.y + xb.z * xb.z + xb.w * xb.w;
  float y2 = ya.x * ya.x + ya.y * ya.y + ya.z * ya.z + ya.w * ya.w +
             yb.x * yb.x + yb.y * yb.y + yb.z * yb.z + yb.w * yb.w;
  float dot = xa.x * ya.x + xa.y * ya.y + xa.z * ya.z + xa.w * ya.w +
              xb.x * yb.x + xb.y * yb.y + xb.z * yb.z + xb.w * yb.w;
  float D = (x2 + y2) - 2.0f * dot;   // mirrors reference expansion
  Dws[((size_t)b * DPAD + n) * 64 + lane] = valid ? D : __builtin_inff();
}

// ---------------------------------------------------------------------------
// Kernel 2: bare DTW sweep, 1 wave/batch, launch_bounds(64,1) => 512-VGPR
// budget so qA[64]+qB[64] stay register-resident. d1/d2 are compile-time:
//  - chunks 0 and 15: fully static (literal base, lo_of folds)
//  - chunks 1..14 (n=64..959, steady band region): d2==1, d1=(n even)
// Per steady step: 1 dpp + v_min3 + v_add + store. No LDS, no barriers.
// ---------------------------------------------------------------------------
__global__ __launch_bounds__(64, 1) void dtw_reg_kernel(const float* __restrict__ Dws,
                                                        float* __restrict__ Rdiag,
                                                        float* __restrict__ out) {
  const int b = blockIdx.x;
  const int lane = threadIdx.x;
  const float INF = __builtin_inff();

  const float* __restrict__ Db = Dws + (size_t)b * DPAD * 64 + lane;
  float* __restrict__ Rd = Rdiag + (size_t)b * DPAD * 64 + lane;

  float qA[CHUNK], qB[CHUNK];

#define LOAD_CHUNK(q, cRt)                                                  \
  { const float* _s = Db + (size_t)(cRt) * (CHUNK * 64);                    \
    _Pragma("unroll")                                                       \
    for (int m = 0; m < CHUNK; ++m) (q)[m] = _s[(size_t)m * 64]; }

  // static-chunk body: BASE is a literal => lon/d1/d2 fold at compile time
#define CHUNK_BODY(q, BASE)                                                 \
  { float* _d = Rd + (size_t)(BASE) * 64;                                   \
    _Pragma("unroll")                                                       \
    for (int m = 0; m < CHUNK; ++m) {                                       \
      const int n = (BASE) + m;                                             \
      const int lon = lo_of(n);                                             \
      const int d1 = lon - lo_of(n - 1);                                    \
      const int d2 = lon - lo_of(n - 2);                                    \
      float s_shl = dpp_shl1(r_d, INF);                                     \
      float s_shr = dpp_shr1(r_d, INF);                                     \
      float tt = d1 ? s_shl : s_shr;                                        \
      float vc = (d2 == 0) ? shm_shr : ((d2 == 1) ? r_dm1 : shm_shl);       \
      float r = (q)[m] + fminf(fminf(r_d, tt), vc);                         \
      _d[(size_t)m * 64] = r;                                               \
      r_dm1 = r_d; shm_shl = s_shl; shm_shr = s_shr; r_d = r;               \
    } }

  // steady body (n in [52,972]): d2==1 -> vc=r_dm1; d1 = (n even) = (m even)
#define CHUNK_STEADY(q, cRt)                                                \
  { float* _d = Rd + (size_t)(cRt) * (CHUNK * 64);                          \
    _Pragma("unroll")                                                       \
    for (int m = 0; m < CHUNK; ++m) {                                       \
      float tt = ((m & 1) == 0) ? dpp_shl1(r_d, INF) : dpp_shr1(r_d, INF);  \
      float r = (q)[m] + fminf(fminf(r_d, tt), r_dm1);                      \
      _d[(size_t)m * 64] = r;                                               \
      r_dm1 = r_d; r_d = r;                                                 \
    } }

  // recurrence state; shm_shr seeded so n=0 (d2==0) yields rmin=0 at lane 0.
  float r_d = INF, r_dm1 = INF, shm_shl = INF;
  float shm_shr = (lane == 0) ? 0.0f : INF;

  LOAD_CHUNK(qA, 0)
  LOAD_CHUNK(qB, 1)
  CHUNK_BODY(qA, 0)                 // chunk 0 static (band entry transitions)
#pragma unroll 1
  for (int c = 1; c <= 13; c += 2) {
    LOAD_CHUNK(qA, c + 1)
    CHUNK_STEADY(qB, c)             // odd chunk
    LOAD_CHUNK(qB, c + 2)
    CHUNK_STEADY(qA, c + 1)         // even chunk
  }
  CHUNK_BODY(qB, 960)               // chunk 15 static (band exit + pad)

  // r_d = padded diag 1023 (INF), r_dm1 = diag 1022.
  if (lane == 0) out[b] = r_dm1;    // lane0 of diag 1022 = R[511][511]
#undef LOAD_CHUNK
#undef CHUNK_BODY
#undef CHUNK_STEADY
}

// ---------------------------------------------------------------------------
// Kernel 3: transpose Rdiag (diag-major) -> Rfull rows (proven R6-R9).
// ---------------------------------------------------------------------------
__global__ __launch_bounds__(256) void transpose_kernel(const float* __restrict__ Rdiag,
                                                        float* __restrict__ out) {
  __shared__ float T[CHUNK][65];
  const int b = blockIdx.x >> 4;
  const int cc = blockIdx.x & 15;
  const int t = threadIdx.x;
  const int w = t >> 6, lane = t & 63;

  float* __restrict__ Rfull = out + BATCH + (size_t)b * RDIM * RDIM;
  if (cc == 0 && t == 0) Rfull[0] = 0.0f;   // R[b][0][0] = 0

  const float4* src4 = (const float4*)(Rdiag + ((size_t)b * DPAD + cc * CHUNK) * 64);
#pragma unroll
  for (int k = 0; k < 4; ++k) {
    const int idx4 = t + k * 256;            // 1024 float4 = 4096 floats
    float4 f = src4[idx4];
    const int linear = idx4 * 4;
    const int dd = linear >> 6, l = linear & 63;
    T[dd][l] = f.x; T[dd][l + 1] = f.y; T[dd][l + 2] = f.z; T[dd][l + 3] = f.w;
  }
  __syncthreads();

  const int dlo = cc * CHUNK;
  const int dhi1 = min(dlo + CHUNK - 1, NDIAG - 1);   // last real diag in chunk
  const int rlo = lo_of(dlo);
  const int rhi = hi_of(dhi1);

  for (int i = rlo + w; i <= rhi; i += 4) {
    const int j0 = max(max(i - WB, dlo - i), 0);
    const int j1 = min(min(i + WB, dhi1 - i), NN - 1);
    const int j = j0 + lane;
    if (j <= j1) {
      const int n = i + j;
      const int dd = n - dlo;
      const int l2 = i - lo_of(n);
      Rfull[(size_t)(i + 1) * RDIM + (j + 1)] = T[dd][l2];
    }
  }
}

// ---------------------------------------------------------------------------
// Fallback (ws too small): proven R3-style kernel (no workspace needed).
// ---------------------------------------------------------------------------
__global__ __launch_bounds__(256) void dtw_fb_kernel(const float* __restrict__ X,
                                                     const float* __restrict__ Y,
                                                     float* __restrict__ out) {
  __shared__ float xsT[DIMS][NN];
  __shared__ float ysT[DIMS][NN];
  __shared__ float x2s[NN];
  __shared__ float y2s[NN];
  __shared__ float ring[2][CHUNK][64];

  const int b = blockIdx.x;
  const int t = threadIdx.x;
  const float INF = __builtin_inff();

  {
    const float4* Xg = (const float4*)(X + (size_t)b * NN * DIMS);
    const float4* Yg = (const float4*)(Y + (size_t)b * NN * DIMS);
    for (int r = t; r < NN; r += 256) {
      float4 a0 = Xg[2 * r], a1 = Xg[2 * r + 1];
      xsT[0][r] = a0.x; xsT[1][r] = a0.y; xsT[2][r] = a0.z; xsT[3][r] = a0.w;
      xsT[4][r] = a1.x; xsT[5][r] = a1.y; xsT[6][r] = a1.z; xsT[7][r] = a1.w;
      x2s[r] = a0.x * a0.x + a0.y * a0.y + a0.z * a0.z + a0.w * a0.w +
               a1.x * a1.x + a1.y * a1.y + a1.z * a1.z + a1.w * a1.w;
      float4 c0 = Yg[2 * r], c1 = Yg[2 * r + 1];
      ysT[0][r] = c0.x; ysT[1][r] = c0.y; ysT[2][r] = c0.z; ysT[3][r] = c0.w;
      ysT[4][r] = c1.x; ysT[5][r] = c1.y; ysT[6][r] = c1.z; ysT[7][r] = c1.w;
      y2s[r] = c0.x * c0.x + c0.y * c0.y + c0.z * c0.z + c0.w * c0.w +
               c1.x * c1.x + c1.y * c1.y + c1.z * c1.z + c1.w * c1.w;
    }
  }
  __syncthreads();

  float* __restrict__ Rfull = out + BATCH + (size_t)b * RDIM * RDIM;
  if (t == 64) Rfull[0] = 0.0f;

  const int lane = t & 63;
  float r_d = INF, r_dm1 = INF;
  int lop = 0, lopp = 0;
  float Dcur = 0.0f;
  if (t < 64) {
    int i0 = min(lane, NN - 1);
    int j0 = max(0, min(0 - i0, NN - 1));
    float dot = xsT[0][i0] * ysT[0][j0] + xsT[1][i0] * ysT[1][j0] +
                xsT[2][i0] * ysT[2][j0] + xsT[3][i0] * ysT[3][j0] +
                xsT[4][i0] * ysT[4][j0] + xsT[5][i0] * ysT[5][j0] +
                xsT[6][i0] * ysT[6][j0] + xsT[7][i0] * ysT[7][j0];
    Dcur = (x2s[i0] + y2s[j0]) - 2.0f * dot;
  }

  for (int c = 0; c <= NCHUNK; ++c) {
    if (t < 64 && c < NCHUNK) {
      const int dlo = c * CHUNK;
      const int dhi = min(dlo + CHUNK, NDIAG);
      for (int n = dlo; n < dhi; ++n) {
        const int lon = lo_of(n), hin = hi_of(n);
        const int d1 = lon - lop;
        const int d2 = lon - lopp;
        const int sa = lane + d1;
        const int sb = sa - 1;
        const int sc = lane + d2 - 1;
        float va = __shfl(r_d, sa);   va = (sa < 64) ? va : INF;
        float vb = __shfl(r_d, sb);   vb = (sb >= 0) ? vb : INF;
        float vc = __shfl(r_dm1, sc); vc = (sc >= 0 && sc < 64) ? vc : INF;
        float rmin = fminf(fminf(vc, vb), va);
        if (n == 0) rmin = (lane == 0) ? 0.0f : INF;
        float r = Dcur + rmin;
        if (lane > hin - lon) r = INF;
        ring[c & 1][n - dlo][lane] = r;
        const int lon1 = lo_of(n + 1);
        int ii = min(lon1 + lane, NN - 1);
        int jj = n + 1 - ii; jj = max(0, min(jj, NN - 1));
        float dot = xsT[0][ii] * ysT[0][jj] + xsT[1][ii] * ysT[1][jj] +
                    xsT[2][ii] * ysT[2][jj] + xsT[3][ii] * ysT[3][jj] +
                    xsT[4][ii] * ysT[4][jj] + xsT[5][ii] * ysT[5][jj] +
                    xsT[6][ii] * ysT[6][jj] + xsT[7][ii] * ysT[7][jj];
        Dcur = (x2s[ii] + y2s[jj]) - 2.0f * dot;
        r_dm1 = r_d; r_d = r;
        lopp = lop; lop = lon;
      }
    } else if (t >= 64 && c >= 1) {
      const int dlo = (c - 1) * CHUNK;
      const int dhi = min(dlo + CHUNK, NDIAG);
      const int nslots = (dhi - dlo) * 64;
      const int buf = (c - 1) & 1;
      for (int s = t - 64; s < nslots; s += 192) {
        const int dd = s >> 6, l2 = s & 63;
        const int n = dlo + dd;
        const int lon = lo_of(n);
        const int i = lon + l2;
        if (i <= hi_of(n)) {
          Rfull[(size_t)(i + 1) * RDIM + (n - i + 1)] = ring[buf][dd][l2];
        }
      }
    }
    __syncthreads();
  }

  if (t == 0) out[b] = r_d;
}

extern "C" void kernel_launch(void* const* d_in, const int* in_sizes, int n_in,
                              void* d_out, int out_size, void* d_ws, size_t ws_size,
                              hipStream_t stream) {
  const float* X = (const float*)d_in[0];
  const float* Y = (const float*)d_in[1];
  float* out = (float*)d_out;

  const size_t needD = (size_t)BATCH * DPAD * 64 * sizeof(float);  // 16.78 MB
  const size_t need = 2 * needD;                                   // Dws + Rdiag
  if (ws_size >= need) {
    float* Dws = (float*)d_ws;
    float* Rdiag = (float*)d_ws + (size_t)BATCH * DPAD * 64;
    dpre_kernel<<<(BATCH * DPAD) / 4, 256, 0, stream>>>(X, Y, Dws);
    dtw_reg_kernel<<<BATCH, 64, 0, stream>>>(Dws, Rdiag, out);
    transpose_kernel<<<BATCH * NCHUNK, 256, 0, stream>>>(Rdiag, out);
  } else {
    dtw_fb_kernel<<<BATCH, 256, 0, stream>>>(X, Y, out);
  }
}